// Round 1
// baseline (423.388 us; speedup 1.0000x reference)
//
#include <hip/hip_runtime.h>
#include <stdint.h>

#define IN_F 4096
#define OUT_F 4096
#define M_ROWS 8192

// NF4 codebook pre-scaled to int8: round(c * 127)
__device__ __constant__ int c_nf4_i8[16] = {
    -127, -88, -67, -50, -36, -23, -12, 0, 10, 20, 31, 43, 56, 71, 92, 127};

typedef int i32x4 __attribute__((ext_vector_type(4)));
typedef int i32x16 __attribute__((ext_vector_type(16)));

// ---------------------------------------------------------------------------
// Quantize x per row: one block per row (4096 fp32). Each thread handles 16
// floats (4x float4, coalesced), block-reduces absmax, writes int8 + step.
// ---------------------------------------------------------------------------
__global__ __launch_bounds__(256) void k_quant_x(
    const float* __restrict__ x, signed char* __restrict__ xq,
    float* __restrict__ steps) {
  const int row = blockIdx.x;
  const int tid = threadIdx.x;
  const float4* xr = (const float4*)(x + (size_t)row * IN_F);
  float4 v[4];
  float m = 0.0f;
#pragma unroll
  for (int i = 0; i < 4; ++i) {
    v[i] = xr[tid + 256 * i];
    m = fmaxf(m, fmaxf(fmaxf(fabsf(v[i].x), fabsf(v[i].y)),
                       fmaxf(fabsf(v[i].z), fabsf(v[i].w))));
  }
#pragma unroll
  for (int off = 32; off > 0; off >>= 1) m = fmaxf(m, __shfl_xor(m, off));
  __shared__ float wmax[4];
  if ((tid & 63) == 0) wmax[tid >> 6] = m;
  __syncthreads();
  m = fmaxf(fmaxf(wmax[0], wmax[1]), fmaxf(wmax[2], wmax[3]));
  const float inv = (m > 0.0f) ? 127.0f / m : 0.0f;
  if (tid == 0) steps[row] = m * (1.0f / 127.0f);
  int* oq = (int*)(xq + (size_t)row * IN_F);
#pragma unroll
  for (int i = 0; i < 4; ++i) {
    int q0 = (int)rintf(v[i].x * inv);
    int q1 = (int)rintf(v[i].y * inv);
    int q2 = (int)rintf(v[i].z * inv);
    int q3 = (int)rintf(v[i].w * inv);
    oq[tid + 256 * i] =
        (q0 & 255) | ((q1 & 255) << 8) | ((q2 & 255) << 16) | (q3 << 24);
  }
}

// ---------------------------------------------------------------------------
// Dequantize NF4 -> int8 codebook values (scale folded into GEMM epilogue).
// ---------------------------------------------------------------------------
__global__ __launch_bounds__(256) void k_dequant(
    const int* __restrict__ packed, signed char* __restrict__ W) {
  __shared__ short lut[256];
  {
    const int b = threadIdx.x;
    const int lo = c_nf4_i8[b & 15], hi = c_nf4_i8[b >> 4];
    lut[b] = (short)((lo & 0xFF) | ((hi & 0xFF) << 8));
  }
  __syncthreads();
  const int tid = blockIdx.x * 256 + threadIdx.x;
  const int4 ca = ((const int4*)packed)[2 * tid];
  const int4 cb = ((const int4*)packed)[2 * tid + 1];
  union { short h[8]; int4 v; } o;
  o.h[0] = lut[ca.x]; o.h[1] = lut[ca.y]; o.h[2] = lut[ca.z]; o.h[3] = lut[ca.w];
  o.h[4] = lut[cb.x]; o.h[5] = lut[cb.y]; o.h[6] = lut[cb.z]; o.h[7] = lut[cb.w];
  ((int4*)W)[tid] = o.v;
}

// ---------------------------------------------------------------------------
// int8 GEMM, NT: C = A * B^T.  256x256 block tile, BK=128 (bytes==elements),
// 512 threads = 8 waves (2M x 4N), per-wave 128x64 output (4x2 frags of
// 32x32, frags split across tile halves: wave wm owns rows wm*64+{0,32} of
// half0 AND half1 so phase (mh,nh) reads only A-half mh / B-half nh).
//
// 8-phase schedule, 2 K-tiles per iteration (buf0 = even tiles, buf1 = odd):
//   p1 (b0,mh0,nh0) stage Y.A.h1(cur)   p5 (b1,mh0,nh0) stage X.A.h1(next)
//   p2 (b0,mh0,nh1) stage Y.B.h1(cur)   p6 (b1,mh0,nh1) stage X.B.h1(next)
//   p3 (b0,mh1,nh0) stage X.A.h0(next)  p7 (b1,mh1,nh0) stage Y.A.h0(next)
//   p4 (b0,mh1,nh1) stage X.B.h0(next)  p8 (b1,mh1,nh1) stage Y.B.h0(next)
//   counted s_waitcnt vmcnt(4) ONLY at p4/p8 (never 0 in the main loop).
// Death/arrival schedule verified: every staged half is last-read >=1 phase
// before its stage issues (raw-barrier separated) and lands before first
// read (covered by the vmcnt(4) at the preceding p4/p8 boundary).
//
// Bank-conflict-free LDS: rows are 128 B; 16-B chunk c of row r stored at
// chunk c ^ (r&7), applied on the GLOBAL source side of global_load_lds
// (LDS dest must stay base + lane*16) and undone on the ds_read side.
// ---------------------------------------------------------------------------
#define GLL(gptr, lptr)                                          \
  __builtin_amdgcn_global_load_lds(                              \
      (__attribute__((address_space(1))) void*)(gptr),           \
      (__attribute__((address_space(3))) void*)(lptr), 16, 0, 0)

#define FENCE() asm volatile("" ::: "memory")

__device__ __forceinline__ void gemm_phase(
    const signed char* SA, const signed char* SB, int mh, int nh,
    int wm, int wn, int r31, int khalf, int ln7, int w,
    i32x16& acc0, i32x16& acc1,
    const signed char* gsrc, signed char* ldst, int kt, int doStage,
    int waitMode) {
  i32x4 a0[4], a1[4], b[4];
#pragma unroll
  for (int ks = 0; ks < 4; ++ks) {
    const int ch = ((2 * ks + khalf) ^ ln7) * 16;
    a0[ks] = *(const i32x4*)&SA[(wm * 64 + mh * 128 + r31) * 128 + ch];
    a1[ks] = *(const i32x4*)&SA[(wm * 64 + mh * 128 + 32 + r31) * 128 + ch];
    b[ks]  = *(const i32x4*)&SB[(wn * 32 + nh * 128 + r31) * 128 + ch];
  }
  if (doStage) {
#pragma unroll
    for (int g = 0; g < 2; ++g)
      GLL(gsrc + (size_t)(g * 64) * IN_F + (size_t)kt * 128,
          ldst + (g * 64 + w * 8) * 128);
  }
  FENCE();
  __builtin_amdgcn_s_barrier();
  FENCE();
  __builtin_amdgcn_s_setprio(1);
#pragma unroll
  for (int ks = 0; ks < 4; ++ks) {
    acc0 = __builtin_amdgcn_mfma_i32_32x32x32_i8(a0[ks], b[ks], acc0, 0, 0, 0);
    acc1 = __builtin_amdgcn_mfma_i32_32x32x32_i8(a1[ks], b[ks], acc1, 0, 0, 0);
  }
  __builtin_amdgcn_s_setprio(0);
  if (waitMode == 1) {
    asm volatile("s_waitcnt vmcnt(4)" ::: "memory");
  } else if (waitMode == 2) {
    asm volatile("s_waitcnt vmcnt(0)" ::: "memory");
  }
  FENCE();
  __builtin_amdgcn_s_barrier();
  FENCE();
}

__global__ __launch_bounds__(512, 2) void k_gemm(
    const signed char* __restrict__ A,   // [M_ROWS][IN_F] int8
    const signed char* __restrict__ B,   // [OUT_F][IN_F] int8
    const float* __restrict__ steps,     // [M_ROWS] per-row x step
    const float* __restrict__ scale,     // [OUT_F] per-channel w scale
    const float* __restrict__ bias,      // [OUT_F]
    float* __restrict__ C) {             // [M_ROWS][OUT_F] fp32
  __shared__ __align__(16) signed char sA[2][256 * 128];
  __shared__ __align__(16) signed char sB[2][256 * 128];
  const int tid = threadIdx.x;
  const int lane = tid & 63;
  const int w = tid >> 6;     // wave 0..7
  const int wm = w >> 2;      // 0..1
  const int wn = w & 3;       // 0..3
  const int r31 = lane & 31;
  const int khalf = lane >> 5;
  const int ln7 = lane & 7;

  // Bijective XCD-aware swizzle: 512 wgs, 8 XCDs, 64 per chunk.
  const int orig = blockIdx.x;
  const int swz = (orig & 7) * 64 + (orig >> 3);
  const int bn = (swz & 15) * 256;   // OUT_F/256 = 16
  const int bm = (swz >> 4) * 256;   // M_ROWS/256 = 32

  // Staging: wave w, GLL round g covers rows g*64 + w*8 + (lane>>3) of a
  // 128-row half; LDS chunk lane&7 must hold global chunk (lane&7)^(row&7),
  // row&7 == lane>>3.
  const int tr = w * 8 + (lane >> 3);
  const int schnk = (lane & 7) ^ (lane >> 3);
  const signed char* gA = A + (size_t)(bm + tr) * IN_F + schnk * 16;
  const signed char* gB = B + (size_t)(bn + tr) * IN_F + schnk * 16;

  i32x16 acc[2][2][2] = {};  // [mh][f][nh]

  auto stage2 = [&](const signed char* gsrc, signed char* ldst, int kt) {
#pragma unroll
    for (int g = 0; g < 2; ++g)
      GLL(gsrc + (size_t)(g * 64) * IN_F + (size_t)kt * 128,
          ldst + (g * 64 + w * 8) * 128);
  };

  // Prologue: tile0 (buf0) fully; tile1 (buf1) half0 of A and B.  12 GLLs;
  // vmcnt(4) leaves the 4 tile1 loads in flight, all of tile0 landed.
  stage2(gA, &sA[0][0], 0);
  stage2(gA + (size_t)128 * IN_F, &sA[0][128 * 128], 0);
  stage2(gB, &sB[0][0], 0);
  stage2(gB + (size_t)128 * IN_F, &sB[0][128 * 128], 0);
  stage2(gA, &sA[1][0], 1);
  stage2(gB, &sB[1][0], 1);
  asm volatile("s_waitcnt vmcnt(4)" ::: "memory");
  FENCE();
  __builtin_amdgcn_s_barrier();
  FENCE();

#pragma unroll 1
  for (int it = 0; it < 16; ++it) {
    const int nl = (it < 15) ? 1 : 0;
    const int kY = 2 * it + 1;
    const int kXn = 2 * it + 2;
    const int kYn = 2 * it + 3;
    // p1
    gemm_phase(sA[0], sB[0], 0, 0, wm, wn, r31, khalf, ln7, w,
               acc[0][0][0], acc[0][1][0],
               gA + (size_t)128 * IN_F, &sA[1][128 * 128], kY, 1, 0);
    // p2
    gemm_phase(sA[0], sB[0], 0, 1, wm, wn, r31, khalf, ln7, w,
               acc[0][0][1], acc[0][1][1],
               gB + (size_t)128 * IN_F, &sB[1][128 * 128], kY, 1, 0);
    // p3
    gemm_phase(sA[0], sB[0], 1, 0, wm, wn, r31, khalf, ln7, w,
               acc[1][0][0], acc[1][1][0],
               gA, &sA[0][0], kXn, nl, 0);
    // p4  (vmcnt(4); last iter drains to 0 so p1/p2's Y.h1 are readable)
    gemm_phase(sA[0], sB[0], 1, 1, wm, wn, r31, khalf, ln7, w,
               acc[1][0][1], acc[1][1][1],
               gB, &sB[0][0], kXn, nl, nl ? 1 : 2);
    // p5
    gemm_phase(sA[1], sB[1], 0, 0, wm, wn, r31, khalf, ln7, w,
               acc[0][0][0], acc[0][1][0],
               gA + (size_t)128 * IN_F, &sA[0][128 * 128], kXn, nl, 0);
    // p6
    gemm_phase(sA[1], sB[1], 0, 1, wm, wn, r31, khalf, ln7, w,
               acc[0][0][1], acc[0][1][1],
               gB + (size_t)128 * IN_F, &sB[0][128 * 128], kXn, nl, 0);
    // p7
    gemm_phase(sA[1], sB[1], 1, 0, wm, wn, r31, khalf, ln7, w,
               acc[1][0][0], acc[1][1][0],
               gA, &sA[1][0], kYn, nl, 0);
    // p8
    gemm_phase(sA[1], sB[1], 1, 1, wm, wn, r31, khalf, ln7, w,
               acc[1][0][1], acc[1][1][1],
               gB, &sB[1][0], kYn, nl, nl ? 1 : 0);
  }

  // Epilogue: 32x32 D layout col = lane&31, row = (reg&3)+8*(reg>>2)+4*khalf
  // (verified layout, re-based to the half-split frag positions).
#pragma unroll
  for (int mh = 0; mh < 2; ++mh) {
#pragma unroll
    for (int f = 0; f < 2; ++f) {
      const int row0 = bm + wm * 64 + mh * 128 + f * 32 + 4 * khalf;
#pragma unroll
      for (int nh = 0; nh < 2; ++nh) {
        const int col = bn + wn * 32 + nh * 128 + r31;
        const float fc = scale[col] * (1.0f / 127.0f);
        const float bv = bias[col];
#pragma unroll
        for (int reg = 0; reg < 16; ++reg) {
          const int row = row0 + (reg & 3) + 8 * (reg >> 2);
          C[(size_t)row * OUT_F + col] =
              (float)acc[mh][f][nh][reg] * (steps[row] * fc) + bv;
        }
      }
    }
  }
}

extern "C" void kernel_launch(void* const* d_in, const int* in_sizes, int n_in,
                              void* d_out, int out_size, void* d_ws, size_t ws_size,
                              hipStream_t stream) {
  const float* x      = (const float*)d_in[0];   // [4,2048,4096] fp32
  const int* packed   = (const int*)d_in[1];     // [OUT_F*IN_F/2] int32
  const float* scale  = (const float*)d_in[2];   // [OUT_F,1] fp32
  const float* bias   = (const float*)d_in[3];   // [OUT_F] fp32
  float* out = (float*)d_out;                    // [4,2048,4096] fp32

  signed char* Xq = (signed char*)d_ws;                         // 33.5 MB
  signed char* Wq = Xq + (size_t)M_ROWS * IN_F;                 // 16.8 MB
  float* steps = (float*)(Wq + (size_t)OUT_F * IN_F);           // 32 KB

  k_quant_x<<<M_ROWS, 256, 0, stream>>>(x, Xq, steps);
  k_dequant<<<(OUT_F * IN_F / 2) / (256 * 8), 256, 0, stream>>>(packed, Wq);
  k_gemm<<<(OUT_F / 256) * (M_ROWS / 256), 512, 0, stream>>>(
      Xq, Wq, steps, scale, bias, out);
}

// Round 2
// 378.694 us; speedup vs baseline: 1.1180x; 1.1180x over previous
//
#include <hip/hip_runtime.h>
#include <stdint.h>

#define IN_F 4096
#define OUT_F 4096
#define M_ROWS 8192

// NF4 codebook pre-scaled to int8: round(c * 127)
__device__ __constant__ int c_nf4_i8[16] = {
    -127, -88, -67, -50, -36, -23, -12, 0, 10, 20, 31, 43, 56, 71, 92, 127};

typedef int i32x4 __attribute__((ext_vector_type(4)));
typedef int i32x16 __attribute__((ext_vector_type(16)));

// ---------------------------------------------------------------------------
// Quantize x per row: one block per row (4096 fp32). Each thread handles 16
// floats (4x float4, coalesced), block-reduces absmax, writes int8 + step.
// ---------------------------------------------------------------------------
__global__ __launch_bounds__(256) void k_quant_x(
    const float* __restrict__ x, signed char* __restrict__ xq,
    float* __restrict__ steps) {
  const int row = blockIdx.x;
  const int tid = threadIdx.x;
  const float4* xr = (const float4*)(x + (size_t)row * IN_F);
  float4 v[4];
  float m = 0.0f;
#pragma unroll
  for (int i = 0; i < 4; ++i) {
    v[i] = xr[tid + 256 * i];
    m = fmaxf(m, fmaxf(fmaxf(fabsf(v[i].x), fabsf(v[i].y)),
                       fmaxf(fabsf(v[i].z), fabsf(v[i].w))));
  }
#pragma unroll
  for (int off = 32; off > 0; off >>= 1) m = fmaxf(m, __shfl_xor(m, off));
  __shared__ float wmax[4];
  if ((tid & 63) == 0) wmax[tid >> 6] = m;
  __syncthreads();
  m = fmaxf(fmaxf(wmax[0], wmax[1]), fmaxf(wmax[2], wmax[3]));
  const float inv = (m > 0.0f) ? 127.0f / m : 0.0f;
  if (tid == 0) steps[row] = m * (1.0f / 127.0f);
  int* oq = (int*)(xq + (size_t)row * IN_F);
#pragma unroll
  for (int i = 0; i < 4; ++i) {
    int q0 = (int)rintf(v[i].x * inv);
    int q1 = (int)rintf(v[i].y * inv);
    int q2 = (int)rintf(v[i].z * inv);
    int q3 = (int)rintf(v[i].w * inv);
    oq[tid + 256 * i] =
        (q0 & 255) | ((q1 & 255) << 8) | ((q2 & 255) << 16) | (q3 << 24);
  }
}

// ---------------------------------------------------------------------------
// Dequantize NF4 -> int8 codebook values (scale folded into GEMM epilogue).
// ---------------------------------------------------------------------------
__global__ __launch_bounds__(256) void k_dequant(
    const int* __restrict__ packed, signed char* __restrict__ W) {
  __shared__ short lut[256];
  {
    const int b = threadIdx.x;
    const int lo = c_nf4_i8[b & 15], hi = c_nf4_i8[b >> 4];
    lut[b] = (short)((lo & 0xFF) | ((hi & 0xFF) << 8));
  }
  __syncthreads();
  const int tid = blockIdx.x * 256 + threadIdx.x;
  const int4 ca = ((const int4*)packed)[2 * tid];
  const int4 cb = ((const int4*)packed)[2 * tid + 1];
  union { short h[8]; int4 v; } o;
  o.h[0] = lut[ca.x]; o.h[1] = lut[ca.y]; o.h[2] = lut[ca.z]; o.h[3] = lut[ca.w];
  o.h[4] = lut[cb.x]; o.h[5] = lut[cb.y]; o.h[6] = lut[cb.z]; o.h[7] = lut[cb.w];
  ((int4*)W)[tid] = o.v;
}

// ---------------------------------------------------------------------------
// int8 GEMM, NT: C = A * B^T.  256x256 tile, BK=128, 512 threads = 8 waves
// (2M x 4N).  Per-wave output 128x64 = 4x2 frags of 32x32.
//
// K-phased 8-phase schedule: phase = ONE k-step over the FULL 4x2 frag grid
// (6 ds_read_b128 -> 8 MFMA, the minimum-read shape for this wave tile).
// p1-p4 consume buf0 (k-steps 0..3), p5-p8 consume buf1.
// Staging (full-tile granularity; k-phased reads touch the whole buffer every
// phase so half-tile staging is illegal):
//   p1: stage buf1.A <- tile 2it+1 (4 GLL)   [skip it==0, prologue did it]
//   p2: stage buf1.B <- tile 2it+1 (4 GLL)
//   p4: s_waitcnt vmcnt(0)   (issue->wait distance ~2-3 phases, latency hidden)
//   p5: stage buf0.A <- tile 2it+2 (4 GLL)   [skip it==15]
//   p6: stage buf0.B <- tile 2it+2 (4 GLL)
//   p8: s_waitcnt vmcnt(0)
// Overwrite safety: a buffer's last reads complete before that phase's end
// barrier (mfma waits lgkm on its own reads before issue), and the restage is
// issued only after that barrier.
//
// Bank-swizzle (carried verbatim from the verified kernel): rows are 128 B;
// 16-B chunk c of row r stored at chunk c ^ (r&7), applied on the GLOBAL
// source side of global_load_lds (LDS dest stays base + lane*16) and undone
// on the ds_read side.
// ---------------------------------------------------------------------------
#define GLL(gptr, lptr)                                          \
  __builtin_amdgcn_global_load_lds(                              \
      (__attribute__((address_space(1))) void*)(gptr),           \
      (__attribute__((address_space(3))) void*)(lptr), 16, 0, 0)

#define FENCE() asm volatile("" ::: "memory")

__device__ __forceinline__ void gemm_phase(
    const signed char* SA, const signed char* SB, const int ks,
    const int wm, const int wn, const int r31, const int khalf,
    const int ln7, const int w, i32x16 (&acc)[4][2],
    const signed char* gsrc, signed char* ldst, const int kt,
    const int doStage, const int waitZero) {
  i32x4 af[4], bf[2];
  const int ch = ((2 * ks + khalf) ^ ln7) * 16;
#pragma unroll
  for (int f = 0; f < 4; ++f)
    af[f] = *(const i32x4*)&SA[(wm * 128 + f * 32 + r31) * 128 + ch];
#pragma unroll
  for (int g = 0; g < 2; ++g)
    bf[g] = *(const i32x4*)&SB[(wn * 64 + g * 32 + r31) * 128 + ch];
  if (doStage) {
#pragma unroll
    for (int st = 0; st < 4; ++st)
      GLL(gsrc + (size_t)(st * 64) * IN_F + (size_t)kt * 128,
          ldst + (st * 64 + w * 8) * 128);
  }
  FENCE();
  __builtin_amdgcn_s_barrier();
  FENCE();
  __builtin_amdgcn_s_setprio(1);
#pragma unroll
  for (int f = 0; f < 4; ++f)
#pragma unroll
    for (int g = 0; g < 2; ++g)
      acc[f][g] =
          __builtin_amdgcn_mfma_i32_32x32x32_i8(af[f], bf[g], acc[f][g], 0, 0, 0);
  __builtin_amdgcn_s_setprio(0);
  if (waitZero) asm volatile("s_waitcnt vmcnt(0)" ::: "memory");
  FENCE();
  __builtin_amdgcn_s_barrier();
  FENCE();
}

__global__ __launch_bounds__(512, 2) void k_gemm(
    const signed char* __restrict__ A,   // [M_ROWS][IN_F] int8
    const signed char* __restrict__ B,   // [OUT_F][IN_F] int8
    const float* __restrict__ steps,     // [M_ROWS] per-row x step
    const float* __restrict__ scale,     // [OUT_F] per-channel w scale
    const float* __restrict__ bias,      // [OUT_F]
    float* __restrict__ C) {             // [M_ROWS][OUT_F] fp32
  __shared__ __align__(16) signed char sA[2][256 * 128];
  __shared__ __align__(16) signed char sB[2][256 * 128];
  const int tid = threadIdx.x;
  const int lane = tid & 63;
  const int w = tid >> 6;     // wave 0..7
  const int wm = w >> 2;      // 0..1  (row half of tile, 128 rows each)
  const int wn = w & 3;       // 0..3  (64-col strip)
  const int r31 = lane & 31;
  const int khalf = lane >> 5;
  const int ln7 = lane & 7;

  // Bijective XCD-aware swizzle: 512 wgs, 8 XCDs, 64 per chunk.
  const int orig = blockIdx.x;
  const int swz = (orig & 7) * 64 + (orig >> 3);
  const int bn = (swz & 15) * 256;   // OUT_F/256 = 16
  const int bm = (swz >> 4) * 256;   // M_ROWS/256 = 32

  // Staging map: wave w, GLL round st covers rows st*64 + w*8 + (lane>>3);
  // LDS chunk lane&7 must hold global chunk (lane&7)^(row&7), row&7==lane>>3.
  const int tr = w * 8 + (lane >> 3);
  const int schnk = (lane & 7) ^ (lane >> 3);
  const signed char* gA = A + (size_t)(bm + tr) * IN_F + schnk * 16;
  const signed char* gB = B + (size_t)(bn + tr) * IN_F + schnk * 16;

  i32x16 acc[4][2] = {};  // [A-frag f][B-frag g]

  auto stage4 = [&](const signed char* gsrc, signed char* ldst, int kt) {
#pragma unroll
    for (int st = 0; st < 4; ++st)
      GLL(gsrc + (size_t)(st * 64) * IN_F + (size_t)kt * 128,
          ldst + (st * 64 + w * 8) * 128);
  };

  // Prologue: buf0 <- tile 0, buf1 <- tile 1.  vmcnt(8): buf0's 8 landed,
  // buf1's 8 still in flight (drained at p4 of it=0).
  stage4(gA, &sA[0][0], 0);
  stage4(gB, &sB[0][0], 0);
  stage4(gA, &sA[1][0], 1);
  stage4(gB, &sB[1][0], 1);
  asm volatile("s_waitcnt vmcnt(8)" ::: "memory");
  FENCE();
  __builtin_amdgcn_s_barrier();
  FENCE();

#pragma unroll 1
  for (int it = 0; it < 16; ++it) {
    const int stY = (it > 0);       // buf1 <- tile 2it+1 (it=0 done in prologue)
    const int stX = (it < 15);      // buf0 <- tile 2it+2
    const int kY = 2 * it + 1;
    const int kX = 2 * it + 2;
    // p1..p4: buf0, k-steps 0..3
    gemm_phase(sA[0], sB[0], 0, wm, wn, r31, khalf, ln7, w, acc,
               gA, &sA[1][0], kY, stY, 0);
    gemm_phase(sA[0], sB[0], 1, wm, wn, r31, khalf, ln7, w, acc,
               gB, &sB[1][0], kY, stY, 0);
    gemm_phase(sA[0], sB[0], 2, wm, wn, r31, khalf, ln7, w, acc,
               gA, &sA[0][0], 0, 0, 0);
    gemm_phase(sA[0], sB[0], 3, wm, wn, r31, khalf, ln7, w, acc,
               gA, &sA[0][0], 0, 0, 1);   // vmcnt(0): buf1 ready
    // p5..p8: buf1, k-steps 0..3
    gemm_phase(sA[1], sB[1], 0, wm, wn, r31, khalf, ln7, w, acc,
               gA, &sA[0][0], kX, stX, 0);
    gemm_phase(sA[1], sB[1], 1, wm, wn, r31, khalf, ln7, w, acc,
               gB, &sB[0][0], kX, stX, 0);
    gemm_phase(sA[1], sB[1], 2, wm, wn, r31, khalf, ln7, w, acc,
               gA, &sA[0][0], 0, 0, 0);
    gemm_phase(sA[1], sB[1], 3, wm, wn, r31, khalf, ln7, w, acc,
               gA, &sA[0][0], 0, 0, 1);   // vmcnt(0): buf0 ready
  }

  // Epilogue: 32x32 D layout col = lane&31, row = (reg&3)+8*(reg>>2)+4*khalf.
#pragma unroll
  for (int f = 0; f < 4; ++f) {
    const int row0 = bm + wm * 128 + f * 32 + 4 * khalf;
#pragma unroll
    for (int g = 0; g < 2; ++g) {
      const int col = bn + wn * 64 + g * 32 + r31;
      const float fc = scale[col] * (1.0f / 127.0f);
      const float bv = bias[col];
#pragma unroll
      for (int reg = 0; reg < 16; ++reg) {
        const int row = row0 + (reg & 3) + 8 * (reg >> 2);
        C[(size_t)row * OUT_F + col] =
            (float)acc[f][g][reg] * (steps[row] * fc) + bv;
      }
    }
  }
}

extern "C" void kernel_launch(void* const* d_in, const int* in_sizes, int n_in,
                              void* d_out, int out_size, void* d_ws, size_t ws_size,
                              hipStream_t stream) {
  const float* x      = (const float*)d_in[0];   // [4,2048,4096] fp32
  const int* packed   = (const int*)d_in[1];     // [OUT_F*IN_F/2] int32
  const float* scale  = (const float*)d_in[2];   // [OUT_F,1] fp32
  const float* bias   = (const float*)d_in[3];   // [OUT_F] fp32
  float* out = (float*)d_out;                    // [4,2048,4096] fp32

  signed char* Xq = (signed char*)d_ws;                         // 33.5 MB
  signed char* Wq = Xq + (size_t)M_ROWS * IN_F;                 // 16.8 MB
  float* steps = (float*)(Wq + (size_t)OUT_F * IN_F);           // 32 KB

  k_quant_x<<<M_ROWS, 256, 0, stream>>>(x, Xq, steps);
  k_dequant<<<(OUT_F * IN_F / 2) / (256 * 8), 256, 0, stream>>>(packed, Wq);
  k_gemm<<<(OUT_F / 256) * (M_ROWS / 256), 512, 0, stream>>>(
      Xq, Wq, steps, scale, bias, out);
}

// Round 3
// 378.495 us; speedup vs baseline: 1.1186x; 1.0005x over previous
//
#include <hip/hip_runtime.h>
#include <stdint.h>

#define IN_F 4096
#define OUT_F 4096
#define M_ROWS 8192

// NF4 codebook pre-scaled to int8: round(c * 127)
__device__ __constant__ int c_nf4_i8[16] = {
    -127, -88, -67, -50, -36, -23, -12, 0, 10, 20, 31, 43, 56, 71, 92, 127};

typedef int i32x4 __attribute__((ext_vector_type(4)));
typedef int i32x16 __attribute__((ext_vector_type(16)));

// ---------------------------------------------------------------------------
// Quantize x per row: one block per row (4096 fp32). Each thread handles 16
// floats (4x float4, coalesced), block-reduces absmax, writes int8 + step.
// ---------------------------------------------------------------------------
__global__ __launch_bounds__(256) void k_quant_x(
    const float* __restrict__ x, signed char* __restrict__ xq,
    float* __restrict__ steps) {
  const int row = blockIdx.x;
  const int tid = threadIdx.x;
  const float4* xr = (const float4*)(x + (size_t)row * IN_F);
  float4 v[4];
  float m = 0.0f;
#pragma unroll
  for (int i = 0; i < 4; ++i) {
    v[i] = xr[tid + 256 * i];
    m = fmaxf(m, fmaxf(fmaxf(fabsf(v[i].x), fabsf(v[i].y)),
                       fmaxf(fabsf(v[i].z), fabsf(v[i].w))));
  }
#pragma unroll
  for (int off = 32; off > 0; off >>= 1) m = fmaxf(m, __shfl_xor(m, off));
  __shared__ float wmax[4];
  if ((tid & 63) == 0) wmax[tid >> 6] = m;
  __syncthreads();
  m = fmaxf(fmaxf(wmax[0], wmax[1]), fmaxf(wmax[2], wmax[3]));
  const float inv = (m > 0.0f) ? 127.0f / m : 0.0f;
  if (tid == 0) steps[row] = m * (1.0f / 127.0f);
  int* oq = (int*)(xq + (size_t)row * IN_F);
#pragma unroll
  for (int i = 0; i < 4; ++i) {
    int q0 = (int)rintf(v[i].x * inv);
    int q1 = (int)rintf(v[i].y * inv);
    int q2 = (int)rintf(v[i].z * inv);
    int q3 = (int)rintf(v[i].w * inv);
    oq[tid + 256 * i] =
        (q0 & 255) | ((q1 & 255) << 8) | ((q2 & 255) << 16) | (q3 << 24);
  }
}

// ---------------------------------------------------------------------------
// Dequantize NF4 -> int8 codebook values (scale folded into GEMM epilogue).
// ---------------------------------------------------------------------------
__global__ __launch_bounds__(256) void k_dequant(
    const int* __restrict__ packed, signed char* __restrict__ W) {
  __shared__ short lut[256];
  {
    const int b = threadIdx.x;
    const int lo = c_nf4_i8[b & 15], hi = c_nf4_i8[b >> 4];
    lut[b] = (short)((lo & 0xFF) | ((hi & 0xFF) << 8));
  }
  __syncthreads();
  const int tid = blockIdx.x * 256 + threadIdx.x;
  const int4 ca = ((const int4*)packed)[2 * tid];
  const int4 cb = ((const int4*)packed)[2 * tid + 1];
  union { short h[8]; int4 v; } o;
  o.h[0] = lut[ca.x]; o.h[1] = lut[ca.y]; o.h[2] = lut[ca.z]; o.h[3] = lut[ca.w];
  o.h[4] = lut[cb.x]; o.h[5] = lut[cb.y]; o.h[6] = lut[cb.z]; o.h[7] = lut[cb.w];
  ((int4*)W)[tid] = o.v;
}

// ---------------------------------------------------------------------------
// int8 GEMM, NT: C = A * B^T.  256x256 tile, BK=128, 512 threads = 8 waves
// (2M x 4N), per-wave 128x64 output (4x2 frags of 32x32).
//
// ONE barrier per K-tile (not per k-step).  Within a tile the buffer is
// stable, so the 4 k-steps need no sync; register loads are software-
// pipelined (two named reg sets, reads(ks+1) issued before MFMAs(ks)) and
// the compiler emits counted lgkmcnt waits, so the LDS pipe (24 reads x 12cy
// = 288cy/wave) overlaps the MFMA pipe (32 x 9.1cy).  R2's measured failure
// mode was exactly this serialization: per-k-step barriers forced
// reads(576) + mfma(585) serial = 1528 cy/phase, MfmaUtil 37%.
//
// Staging: GLLs for buf[nxt] (tile t+1) issue early in tile t (after ks0/ks1
// reads), drain with vmcnt(0) ~2300 cy later at tile end -> latency hidden.
// Overwrite safety: all reads of buf[cur] are lgkm-consumed before the
// tile-end barrier; buf[cur] is restaged only in tile t+1 after that
// barrier.  GLL-vs-read program order within a tile is preserved by the
// compiler (same LDS object).  Static buffer indices (loop unrolled x2).
//
// Bank-swizzle (verbatim from verified kernel): rows are 128 B; 16-B chunk c
// of row r stored at chunk c ^ (r&7), applied on the GLOBAL source side of
// global_load_lds (LDS dest stays base + lane*16), undone on the ds_read.
// ---------------------------------------------------------------------------
#define GLL(gptr, lptr)                                          \
  __builtin_amdgcn_global_load_lds(                              \
      (__attribute__((address_space(1))) void*)(gptr),           \
      (__attribute__((address_space(3))) void*)(lptr), 16, 0, 0)

#define FENCE() asm volatile("" ::: "memory")

__global__ __launch_bounds__(512, 2) void k_gemm(
    const signed char* __restrict__ A,   // [M_ROWS][IN_F] int8
    const signed char* __restrict__ B,   // [OUT_F][IN_F] int8
    const float* __restrict__ steps,     // [M_ROWS] per-row x step
    const float* __restrict__ scale,     // [OUT_F] per-channel w scale
    const float* __restrict__ bias,      // [OUT_F]
    float* __restrict__ C) {             // [M_ROWS][OUT_F] fp32
  __shared__ __align__(16) signed char sA[2][256 * 128];
  __shared__ __align__(16) signed char sB[2][256 * 128];
  const int tid = threadIdx.x;
  const int lane = tid & 63;
  const int w = tid >> 6;     // wave 0..7
  const int wm = w >> 2;      // 0..1  (row half of tile, 128 rows each)
  const int wn = w & 3;       // 0..3  (64-col strip)
  const int r31 = lane & 31;
  const int khalf = lane >> 5;
  const int ln7 = lane & 7;

  // Bijective XCD-aware swizzle: 512 wgs, 8 XCDs, 64 per chunk.
  const int orig = blockIdx.x;
  const int swz = (orig & 7) * 64 + (orig >> 3);
  const int bn = (swz & 15) * 256;   // OUT_F/256 = 16
  const int bm = (swz >> 4) * 256;   // M_ROWS/256 = 32

  // Staging map: wave w, GLL round st covers rows st*64 + w*8 + (lane>>3);
  // LDS chunk lane&7 must hold global chunk (lane&7)^(row&7), row&7==lane>>3.
  const int tr = w * 8 + (lane >> 3);
  const int schnk = (lane & 7) ^ (lane >> 3);
  const signed char* gA = A + (size_t)(bm + tr) * IN_F + schnk * 16;
  const signed char* gB = B + (size_t)(bn + tr) * IN_F + schnk * 16;

  i32x16 acc[4][2] = {};  // [A-frag f][B-frag g]

  auto stage4 = [&](const signed char* gsrc, signed char* ldst, int kt) {
#pragma unroll
    for (int st = 0; st < 4; ++st)
      GLL(gsrc + (size_t)(st * 64) * IN_F + (size_t)kt * 128,
          ldst + (st * 64 + w * 8) * 128);
  };

  // Load one k-step's fragments (6 x ds_read_b128) into a named reg set.
  auto ldfrag = [&](i32x4 (&af)[4], i32x4 (&bf)[2], const signed char* SA_,
                    const signed char* SB_, int ks) {
    const int ch = ((2 * ks + khalf) ^ ln7) * 16;
#pragma unroll
    for (int f = 0; f < 4; ++f)
      af[f] = *(const i32x4*)&SA_[(wm * 128 + f * 32 + r31) * 128 + ch];
#pragma unroll
    for (int g = 0; g < 2; ++g)
      bf[g] = *(const i32x4*)&SB_[(wn * 64 + g * 32 + r31) * 128 + ch];
  };

  auto mfma8 = [&](i32x4 (&af)[4], i32x4 (&bf)[2]) {
    __builtin_amdgcn_s_setprio(1);
#pragma unroll
    for (int f = 0; f < 4; ++f)
#pragma unroll
      for (int g = 0; g < 2; ++g)
        acc[f][g] = __builtin_amdgcn_mfma_i32_32x32x32_i8(af[f], bf[g],
                                                          acc[f][g], 0, 0, 0);
    __builtin_amdgcn_s_setprio(0);
  };

  // One K-tile: 4 k-steps from (SA_,SB_), optionally staging tile tnext into
  // (dA,dB).  Pipelined reads: sets X/Y alternate, reads run ahead of MFMAs.
  auto tile = [&](const signed char* SA_, const signed char* SB_,
                  signed char* dA, signed char* dB, int tnext, int doStage) {
    i32x4 aX[4], bX[2], aY[4], bY[2];
    ldfrag(aX, bX, SA_, SB_, 0);
    ldfrag(aY, bY, SA_, SB_, 1);
    if (doStage) {
      stage4(gA, dA, tnext);
      stage4(gB, dB, tnext);
    }
    mfma8(aX, bX);                 // ks0 (compiler: lgkmcnt(6))
    ldfrag(aX, bX, SA_, SB_, 2);
    mfma8(aY, bY);                 // ks1
    ldfrag(aY, bY, SA_, SB_, 3);
    mfma8(aX, bX);                 // ks2
    mfma8(aY, bY);                 // ks3 (lgkmcnt(0))
    if (doStage) asm volatile("s_waitcnt vmcnt(0)" ::: "memory");
    FENCE();
    __builtin_amdgcn_s_barrier();
    FENCE();
  };

  // Prologue: buf0 <- tile 0.
  stage4(gA, &sA[0][0], 0);
  stage4(gB, &sB[0][0], 0);
  asm volatile("s_waitcnt vmcnt(0)" ::: "memory");
  FENCE();
  __builtin_amdgcn_s_barrier();
  FENCE();

#pragma unroll 1
  for (int t2 = 0; t2 < 32; t2 += 2) {
    tile(&sA[0][0], &sB[0][0], &sA[1][0], &sB[1][0], t2 + 1, 1);
    tile(&sA[1][0], &sB[1][0], &sA[0][0], &sB[0][0], t2 + 2, (t2 + 2 < 32));
  }

  // Epilogue: 32x32 D layout col = lane&31, row = (reg&3)+8*(reg>>2)+4*khalf.
#pragma unroll
  for (int f = 0; f < 4; ++f) {
    const int row0 = bm + wm * 128 + f * 32 + 4 * khalf;
#pragma unroll
    for (int g = 0; g < 2; ++g) {
      const int col = bn + wn * 64 + g * 32 + r31;
      const float fc = scale[col] * (1.0f / 127.0f);
      const float bv = bias[col];
#pragma unroll
      for (int reg = 0; reg < 16; ++reg) {
        const int row = row0 + (reg & 3) + 8 * (reg >> 2);
        C[(size_t)row * OUT_F + col] =
            (float)acc[f][g][reg] * (steps[row] * fc) + bv;
      }
    }
  }
}

extern "C" void kernel_launch(void* const* d_in, const int* in_sizes, int n_in,
                              void* d_out, int out_size, void* d_ws, size_t ws_size,
                              hipStream_t stream) {
  const float* x      = (const float*)d_in[0];   // [4,2048,4096] fp32
  const int* packed   = (const int*)d_in[1];     // [OUT_F*IN_F/2] int32
  const float* scale  = (const float*)d_in[2];   // [OUT_F,1] fp32
  const float* bias   = (const float*)d_in[3];   // [OUT_F] fp32
  float* out = (float*)d_out;                    // [4,2048,4096] fp32

  signed char* Xq = (signed char*)d_ws;                         // 33.5 MB
  signed char* Wq = Xq + (size_t)M_ROWS * IN_F;                 // 16.8 MB
  float* steps = (float*)(Wq + (size_t)OUT_F * IN_F);           // 32 KB

  k_quant_x<<<M_ROWS, 256, 0, stream>>>(x, Xq, steps);
  k_dequant<<<(OUT_F * IN_F / 2) / (256 * 8), 256, 0, stream>>>(packed, Wq);
  k_gemm<<<(OUT_F / 256) * (M_ROWS / 256), 512, 0, stream>>>(
      Xq, Wq, steps, scale, bias, out);
}

// Round 4
// 373.240 us; speedup vs baseline: 1.1344x; 1.0141x over previous
//
#include <hip/hip_runtime.h>
#include <stdint.h>

#define IN_F 4096
#define OUT_F 4096
#define M_ROWS 8192

// NF4 codebook pre-scaled to int8: round(c * 127)
__device__ __constant__ int c_nf4_i8[16] = {
    -127, -88, -67, -50, -36, -23, -12, 0, 10, 20, 31, 43, 56, 71, 92, 127};

typedef int i32x4 __attribute__((ext_vector_type(4)));
typedef int i32x16 __attribute__((ext_vector_type(16)));

// ---------------------------------------------------------------------------
// Quantize x per row: one block per row (4096 fp32). Each thread handles 16
// floats (4x float4, coalesced), block-reduces absmax, writes int8 + step.
// ---------------------------------------------------------------------------
__global__ __launch_bounds__(256) void k_quant_x(
    const float* __restrict__ x, signed char* __restrict__ xq,
    float* __restrict__ steps) {
  const int row = blockIdx.x;
  const int tid = threadIdx.x;
  const float4* xr = (const float4*)(x + (size_t)row * IN_F);
  float4 v[4];
  float m = 0.0f;
#pragma unroll
  for (int i = 0; i < 4; ++i) {
    v[i] = xr[tid + 256 * i];
    m = fmaxf(m, fmaxf(fmaxf(fabsf(v[i].x), fabsf(v[i].y)),
                       fmaxf(fabsf(v[i].z), fabsf(v[i].w))));
  }
#pragma unroll
  for (int off = 32; off > 0; off >>= 1) m = fmaxf(m, __shfl_xor(m, off));
  __shared__ float wmax[4];
  if ((tid & 63) == 0) wmax[tid >> 6] = m;
  __syncthreads();
  m = fmaxf(fmaxf(wmax[0], wmax[1]), fmaxf(wmax[2], wmax[3]));
  const float inv = (m > 0.0f) ? 127.0f / m : 0.0f;
  if (tid == 0) steps[row] = m * (1.0f / 127.0f);
  int* oq = (int*)(xq + (size_t)row * IN_F);
#pragma unroll
  for (int i = 0; i < 4; ++i) {
    int q0 = (int)rintf(v[i].x * inv);
    int q1 = (int)rintf(v[i].y * inv);
    int q2 = (int)rintf(v[i].z * inv);
    int q3 = (int)rintf(v[i].w * inv);
    oq[tid + 256 * i] =
        (q0 & 255) | ((q1 & 255) << 8) | ((q2 & 255) << 16) | (q3 << 24);
  }
}

// ---------------------------------------------------------------------------
// Dequantize NF4 -> int8 codebook values (scale folded into GEMM epilogue).
// ---------------------------------------------------------------------------
__global__ __launch_bounds__(256) void k_dequant(
    const int* __restrict__ packed, signed char* __restrict__ W) {
  __shared__ short lut[256];
  {
    const int b = threadIdx.x;
    const int lo = c_nf4_i8[b & 15], hi = c_nf4_i8[b >> 4];
    lut[b] = (short)((lo & 0xFF) | ((hi & 0xFF) << 8));
  }
  __syncthreads();
  const int tid = blockIdx.x * 256 + threadIdx.x;
  const int4 ca = ((const int4*)packed)[2 * tid];
  const int4 cb = ((const int4*)packed)[2 * tid + 1];
  union { short h[8]; int4 v; } o;
  o.h[0] = lut[ca.x]; o.h[1] = lut[ca.y]; o.h[2] = lut[ca.z]; o.h[3] = lut[ca.w];
  o.h[4] = lut[cb.x]; o.h[5] = lut[cb.y]; o.h[6] = lut[cb.z]; o.h[7] = lut[cb.w];
  ((int4*)W)[tid] = o.v;
}

// ---------------------------------------------------------------------------
// int8 GEMM, NT: C = A * B^T.  256x256 tile, BK=128, 512 threads = 8 waves
// (2M x 4N), per-wave 128x64 output (4x2 frags of 32x32).
//
// R3 post-mortem: C++-level read pipelining gave ZERO LDS/MFMA overlap
// (per-tile 5625 cyc = serial LDS 2816 + MFMA 2343 + 470 barrier; MfmaUtil
// 40% = 2343/5625).  The compiler does not keep ds_read ISSUE ahead of the
// MFMA clusters.  Fix (T3/T4 + rule 18): inline-asm ds_read_b128 pinned in
// program order + explicit counted s_waitcnt lgkmcnt(N) + sched_barrier(0)
// after each wait so MFMAs cannot hoist above their data wait.  Schedule per
// tile (one barrier per K-tile):
//   12 asm reads (ks0,ks1) | 8 GLL | lgkm(6) SB mfma8(ks0)
//   6 reads (ks2) | lgkm(6) SB mfma8(ks1)
//   6 reads (ks3) | lgkm(6) SB mfma8(ks2) | lgkm(0) SB mfma8(ks3)
//   vmcnt(0) (staged tiles only), s_barrier.
// lgkm is FIFO for DS ops; global_load_lds is vmcnt-only, so counts exact.
// Max 12 read-operands live = 48 VGPR (same as R3's pressure).
//
// Staging unchanged: GLLs for buf[nxt] issue early in tile t, drain at tile
// end (distance ~2300 cyc hides HBM/L2 latency).  Overwrite safety: lgkm(0)
// before last mfma cluster => all reads of buf[cur] done before tile-end
// barrier; buf[cur] restaged only after that barrier.
//
// Bank-swizzle (verbatim from verified kernel): rows are 128 B; 16-B chunk c
// of row r stored at chunk c ^ (r&7), applied on the GLOBAL source side of
// global_load_lds (LDS dest stays base + lane*16), undone on the ds_read.
// ---------------------------------------------------------------------------
#define GLL(gptr, lptr)                                          \
  __builtin_amdgcn_global_load_lds(                              \
      (__attribute__((address_space(1))) void*)(gptr),           \
      (__attribute__((address_space(3))) void*)(lptr), 16, 0, 0)

#define AS3(p) ((__attribute__((address_space(3))) const signed char*)(p))

#define DSRO(dst, addr, OFF)                                     \
  asm volatile("ds_read_b128 %0, %1 offset:" #OFF                \
               : "=v"(dst) : "v"(AS3(addr)))

#define LGKM(N)                                                  \
  do {                                                           \
    asm volatile("s_waitcnt lgkmcnt(" #N ")" ::: "memory");      \
    __builtin_amdgcn_sched_barrier(0);                           \
  } while (0)

#define VM0()                                                    \
  do {                                                           \
    asm volatile("s_waitcnt vmcnt(0)" ::: "memory");             \
    __builtin_amdgcn_sched_barrier(0);                           \
  } while (0)

#define BARRIER()                                                \
  do {                                                           \
    asm volatile("" ::: "memory");                               \
    __builtin_amdgcn_s_barrier();                                \
    asm volatile("" ::: "memory");                               \
  } while (0)

__global__ __launch_bounds__(512, 2) void k_gemm(
    const signed char* __restrict__ A,   // [M_ROWS][IN_F] int8
    const signed char* __restrict__ B,   // [OUT_F][IN_F] int8
    const float* __restrict__ steps,     // [M_ROWS] per-row x step
    const float* __restrict__ scale,     // [OUT_F] per-channel w scale
    const float* __restrict__ bias,      // [OUT_F]
    float* __restrict__ C) {             // [M_ROWS][OUT_F] fp32
  __shared__ __align__(16) signed char sA[2][256 * 128];
  __shared__ __align__(16) signed char sB[2][256 * 128];
  const int tid = threadIdx.x;
  const int lane = tid & 63;
  const int w = tid >> 6;     // wave 0..7
  const int wm = w >> 2;      // 0..1  (row half of tile, 128 rows each)
  const int wn = w & 3;       // 0..3  (64-col strip)
  const int r31 = lane & 31;
  const int khalf = lane >> 5;
  const int ln7 = lane & 7;

  // Bijective XCD-aware swizzle: 512 wgs, 8 XCDs, 64 per chunk.
  const int orig = blockIdx.x;
  const int swz = (orig & 7) * 64 + (orig >> 3);
  const int bn = (swz & 15) * 256;   // OUT_F/256 = 16
  const int bm = (swz >> 4) * 256;   // M_ROWS/256 = 32

  // Staging map: wave w, GLL round st covers rows st*64 + w*8 + (lane>>3);
  // LDS chunk lane&7 must hold global chunk (lane&7)^(row&7), row&7==lane>>3.
  const int tr = w * 8 + (lane >> 3);
  const int schnk = (lane & 7) ^ (lane >> 3);
  const signed char* gA = A + (size_t)(bm + tr) * IN_F + schnk * 16;
  const signed char* gB = B + (size_t)(bn + tr) * IN_F + schnk * 16;

  // ds_read bases: A frag f at roA0 + f*4096, B frag g at roB0 + g*4096
  // (asm offset: immediates), k-step chunk ch_ks added per cluster.
  const int roA0 = (wm * 128 + r31) * 128;
  const int roB0 = (wn * 64 + r31) * 128;
  const int ch0 = ((0 + khalf) ^ ln7) * 16;
  const int ch1 = ((2 + khalf) ^ ln7) * 16;
  const int ch2 = ((4 + khalf) ^ ln7) * 16;
  const int ch3 = ((6 + khalf) ^ ln7) * 16;

  i32x16 acc[4][2] = {};  // [A-frag f][B-frag g]

#define MFMA8(a0, a1, a2, a3, b0, b1)                                        \
  do {                                                                       \
    __builtin_amdgcn_s_setprio(1);                                           \
    acc[0][0] = __builtin_amdgcn_mfma_i32_32x32x32_i8(a0, b0, acc[0][0], 0, 0, 0); \
    acc[0][1] = __builtin_amdgcn_mfma_i32_32x32x32_i8(a0, b1, acc[0][1], 0, 0, 0); \
    acc[1][0] = __builtin_amdgcn_mfma_i32_32x32x32_i8(a1, b0, acc[1][0], 0, 0, 0); \
    acc[1][1] = __builtin_amdgcn_mfma_i32_32x32x32_i8(a1, b1, acc[1][1], 0, 0, 0); \
    acc[2][0] = __builtin_amdgcn_mfma_i32_32x32x32_i8(a2, b0, acc[2][0], 0, 0, 0); \
    acc[2][1] = __builtin_amdgcn_mfma_i32_32x32x32_i8(a2, b1, acc[2][1], 0, 0, 0); \
    acc[3][0] = __builtin_amdgcn_mfma_i32_32x32x32_i8(a3, b0, acc[3][0], 0, 0, 0); \
    acc[3][1] = __builtin_amdgcn_mfma_i32_32x32x32_i8(a3, b1, acc[3][1], 0, 0, 0); \
    __builtin_amdgcn_s_setprio(0);                                           \
  } while (0)

#define RD6(A0, A1, A2, A3, B0, B1, SAc, SBc, CH)                            \
  do {                                                                       \
    const signed char* pA = (SAc) + roA0 + (CH);                             \
    const signed char* pB = (SBc) + roB0 + (CH);                             \
    DSRO(A0, pA, 0); DSRO(A1, pA, 4096);                                     \
    DSRO(A2, pA, 8192); DSRO(A3, pA, 12288);                                 \
    DSRO(B0, pB, 0); DSRO(B1, pB, 4096);                                     \
  } while (0)

  auto stage4 = [&](const signed char* gsrc, signed char* ldst, int kt) {
#pragma unroll
    for (int st = 0; st < 4; ++st)
      GLL(gsrc + (size_t)(st * 64) * IN_F + (size_t)kt * 128,
          ldst + (st * 64 + w * 8) * 128);
  };

  auto tile = [&](const signed char* SAc, const signed char* SBc,
                  signed char* dA, signed char* dB, int kt, int doStage) {
    i32x4 xA0, xA1, xA2, xA3, xB0, xB1;   // set X
    i32x4 yA0, yA1, yA2, yA3, yB0, yB1;   // set Y
    RD6(xA0, xA1, xA2, xA3, xB0, xB1, SAc, SBc, ch0);   // ks0 -> X
    RD6(yA0, yA1, yA2, yA3, yB0, yB1, SAc, SBc, ch1);   // ks1 -> Y
    if (doStage) {
      stage4(gA, dA, kt);
      stage4(gB, dB, kt);
    }
    LGKM(6);                                            // ks0 landed
    MFMA8(xA0, xA1, xA2, xA3, xB0, xB1);                // cluster ks0
    RD6(xA0, xA1, xA2, xA3, xB0, xB1, SAc, SBc, ch2);   // ks2 -> X (reuse)
    LGKM(6);                                            // ks1 landed
    MFMA8(yA0, yA1, yA2, yA3, yB0, yB1);                // cluster ks1
    RD6(yA0, yA1, yA2, yA3, yB0, yB1, SAc, SBc, ch3);   // ks3 -> Y (reuse)
    LGKM(6);                                            // ks2 landed
    MFMA8(xA0, xA1, xA2, xA3, xB0, xB1);                // cluster ks2
    LGKM(0);                                            // ks3 landed
    MFMA8(yA0, yA1, yA2, yA3, yB0, yB1);                // cluster ks3
    if (doStage) VM0();
    BARRIER();
  };

  // Prologue: buf0 <- tile 0.
  stage4(gA, &sA[0][0], 0);
  stage4(gB, &sB[0][0], 0);
  VM0();
  BARRIER();

#pragma unroll 1
  for (int t2 = 0; t2 < 32; t2 += 2) {
    tile(&sA[0][0], &sB[0][0], &sA[1][0], &sB[1][0], t2 + 1, 1);
    tile(&sA[1][0], &sB[1][0], &sA[0][0], &sB[0][0], t2 + 2, (t2 + 2 < 32));
  }

  // Epilogue: 32x32 D layout col = lane&31, row = (reg&3)+8*(reg>>2)+4*khalf.
#pragma unroll
  for (int f = 0; f < 4; ++f) {
    const int row0 = bm + wm * 128 + f * 32 + 4 * khalf;
#pragma unroll
    for (int g = 0; g < 2; ++g) {
      const int col = bn + wn * 64 + g * 32 + r31;
      const float fc = scale[col] * (1.0f / 127.0f);
      const float bv = bias[col];
#pragma unroll
      for (int reg = 0; reg < 16; ++reg) {
        const int row = row0 + (reg & 3) + 8 * (reg >> 2);
        C[(size_t)row * OUT_F + col] =
            (float)acc[f][g][reg] * (steps[row] * fc) + bv;
      }
    }
  }
#undef MFMA8
#undef RD6
}

extern "C" void kernel_launch(void* const* d_in, const int* in_sizes, int n_in,
                              void* d_out, int out_size, void* d_ws, size_t ws_size,
                              hipStream_t stream) {
  const float* x      = (const float*)d_in[0];   // [4,2048,4096] fp32
  const int* packed   = (const int*)d_in[1];     // [OUT_F*IN_F/2] int32
  const float* scale  = (const float*)d_in[2];   // [OUT_F,1] fp32
  const float* bias   = (const float*)d_in[3];   // [OUT_F] fp32
  float* out = (float*)d_out;                    // [4,2048,4096] fp32

  signed char* Xq = (signed char*)d_ws;                         // 33.5 MB
  signed char* Wq = Xq + (size_t)M_ROWS * IN_F;                 // 16.8 MB
  float* steps = (float*)(Wq + (size_t)OUT_F * IN_F);           // 32 KB

  k_quant_x<<<M_ROWS, 256, 0, stream>>>(x, Xq, steps);
  k_dequant<<<(OUT_F * IN_F / 2) / (256 * 8), 256, 0, stream>>>(packed, Wq);
  k_gemm<<<(OUT_F / 256) * (M_ROWS / 256), 512, 0, stream>>>(
      Xq, Wq, steps, scale, bias, out);
}

// Round 6
// 370.004 us; speedup vs baseline: 1.1443x; 1.0087x over previous
//
#include <hip/hip_runtime.h>
#include <stdint.h>

#define IN_F 4096
#define OUT_F 4096
#define M_ROWS 8192

// NF4 codebook pre-scaled to int8: round(c * 127)
__device__ __constant__ int c_nf4_i8[16] = {
    -127, -88, -67, -50, -36, -23, -12, 0, 10, 20, 31, 43, 56, 71, 92, 127};

typedef int i32x4 __attribute__((ext_vector_type(4)));
typedef int i32x16 __attribute__((ext_vector_type(16)));

// ---------------------------------------------------------------------------
// Quantize x per row: one block per row (4096 fp32). Each thread handles 16
// floats (4x float4, coalesced), block-reduces absmax, writes int8 + step.
// ---------------------------------------------------------------------------
__global__ __launch_bounds__(256) void k_quant_x(
    const float* __restrict__ x, signed char* __restrict__ xq,
    float* __restrict__ steps) {
  const int row = blockIdx.x;
  const int tid = threadIdx.x;
  const float4* xr = (const float4*)(x + (size_t)row * IN_F);
  float4 v[4];
  float m = 0.0f;
#pragma unroll
  for (int i = 0; i < 4; ++i) {
    v[i] = xr[tid + 256 * i];
    m = fmaxf(m, fmaxf(fmaxf(fabsf(v[i].x), fabsf(v[i].y)),
                       fmaxf(fabsf(v[i].z), fabsf(v[i].w))));
  }
#pragma unroll
  for (int off = 32; off > 0; off >>= 1) m = fmaxf(m, __shfl_xor(m, off));
  __shared__ float wmax[4];
  if ((tid & 63) == 0) wmax[tid >> 6] = m;
  __syncthreads();
  m = fmaxf(fmaxf(wmax[0], wmax[1]), fmaxf(wmax[2], wmax[3]));
  const float inv = (m > 0.0f) ? 127.0f / m : 0.0f;
  if (tid == 0) steps[row] = m * (1.0f / 127.0f);
  int* oq = (int*)(xq + (size_t)row * IN_F);
#pragma unroll
  for (int i = 0; i < 4; ++i) {
    int q0 = (int)rintf(v[i].x * inv);
    int q1 = (int)rintf(v[i].y * inv);
    int q2 = (int)rintf(v[i].z * inv);
    int q3 = (int)rintf(v[i].w * inv);
    oq[tid + 256 * i] =
        (q0 & 255) | ((q1 & 255) << 8) | ((q2 & 255) << 16) | (q3 << 24);
  }
}

// ---------------------------------------------------------------------------
// Dequantize NF4 -> int8 codebook values (scale folded into GEMM epilogue).
// ---------------------------------------------------------------------------
__global__ __launch_bounds__(256) void k_dequant(
    const int* __restrict__ packed, signed char* __restrict__ W) {
  __shared__ short lut[256];
  {
    const int b = threadIdx.x;
    const int lo = c_nf4_i8[b & 15], hi = c_nf4_i8[b >> 4];
    lut[b] = (short)((lo & 0xFF) | ((hi & 0xFF) << 8));
  }
  __syncthreads();
  const int tid = blockIdx.x * 256 + threadIdx.x;
  const int4 ca = ((const int4*)packed)[2 * tid];
  const int4 cb = ((const int4*)packed)[2 * tid + 1];
  union { short h[8]; int4 v; } o;
  o.h[0] = lut[ca.x]; o.h[1] = lut[ca.y]; o.h[2] = lut[ca.z]; o.h[3] = lut[ca.w];
  o.h[4] = lut[cb.x]; o.h[5] = lut[cb.y]; o.h[6] = lut[cb.z]; o.h[7] = lut[cb.w];
  ((int4*)W)[tid] = o.v;
}

// ---------------------------------------------------------------------------
// int8 GEMM, NT: C = A * B^T.  256x256 tile, BK=128, 512 threads = 8 waves
// (2M x 4N), per-wave 128x64 output (4x2 frags of 32x32).
//
// R4 post-mortem: per-tile 5137 cyc = serial LDS(2816) + MFMA(2343); bulk
// read-ahead still alternates pipes (reads only enter the LDS queue after a
// wave finishes issuing its MFMA cluster).  R5's fix (18-deep prefetch) was
// ILLEGAL: lgkmcnt wait encoding is 4-bit (max 15); never exceed 15
// outstanding DS ops.  R6 instead interleaves reads 1:1 INTO the MFMA
// clusters (AITER s02 pattern), pinned with sched_barrier(0): reads issue in
// the MFMA pipe-stall slots, so the LDS unit stays fed during MFMA phases.
//
// lgkm ledger (DS FIFO; GLL is vmcnt-only; max outstanding 12 == proven R4):
//   issue ks0->X, ks1->Y (12) | GLL x8 | lgkm(6): ks0 ready
//   cluster ks0 (MFMA X) interleaved reads ks2->Z   (out 6+6=12)
//   lgkm(6): ks1 ready
//   cluster ks1 (MFMA Y) interleaved reads ks3->X   (X dead since cluster ks0)
//   lgkm(6): ks2 ready  | cluster ks2 (MFMA Z)
//   lgkm(0): ks3 ready  | vmcnt(0) | cluster ks3 (MFMA X) | s_barrier
// WAR safety: a register set is overwritten only a full cluster (>=100s of
// cycles) after its last MFMA read -- same distance R3/R4 ran correctly.
//
// Staging unchanged: GLLs for buf[nxt] at tile start, drained at tile end.
// Bank-swizzle (verbatim): 16-B chunk c of row r stored at chunk c ^ (r&7),
// applied on the GLOBAL source side of global_load_lds, undone on ds_read.
// ---------------------------------------------------------------------------
#define GLL(gptr, lptr)                                          \
  __builtin_amdgcn_global_load_lds(                              \
      (__attribute__((address_space(1))) void*)(gptr),           \
      (__attribute__((address_space(3))) void*)(lptr), 16, 0, 0)

#define AS3(p) ((__attribute__((address_space(3))) const signed char*)(p))

#define DSRO(dst, addr, OFF)                                     \
  asm volatile("ds_read_b128 %0, %1 offset:" #OFF                \
               : "=v"(dst) : "v"(AS3(addr)))

#define SB0() __builtin_amdgcn_sched_barrier(0)

#define LGKM(N)                                                  \
  do {                                                           \
    asm volatile("s_waitcnt lgkmcnt(" #N ")" ::: "memory");      \
    __builtin_amdgcn_sched_barrier(0);                           \
  } while (0)

#define VM0()                                                    \
  do {                                                           \
    asm volatile("s_waitcnt vmcnt(0)" ::: "memory");             \
    __builtin_amdgcn_sched_barrier(0);                           \
  } while (0)

#define BARRIER()                                                \
  do {                                                           \
    asm volatile("" ::: "memory");                               \
    __builtin_amdgcn_s_barrier();                                \
    asm volatile("" ::: "memory");                               \
  } while (0)

__global__ __launch_bounds__(512, 2) void k_gemm(
    const signed char* __restrict__ A,   // [M_ROWS][IN_F] int8
    const signed char* __restrict__ B,   // [OUT_F][IN_F] int8
    const float* __restrict__ steps,     // [M_ROWS] per-row x step
    const float* __restrict__ scale,     // [OUT_F] per-channel w scale
    const float* __restrict__ bias,      // [OUT_F]
    float* __restrict__ C) {             // [M_ROWS][OUT_F] fp32
  __shared__ __align__(16) signed char sA[2][256 * 128];
  __shared__ __align__(16) signed char sB[2][256 * 128];
  const int tid = threadIdx.x;
  const int lane = tid & 63;
  const int w = tid >> 6;     // wave 0..7
  const int wm = w >> 2;      // 0..1  (row half of tile, 128 rows each)
  const int wn = w & 3;       // 0..3  (64-col strip)
  const int r31 = lane & 31;
  const int khalf = lane >> 5;
  const int ln7 = lane & 7;

  // Bijective XCD-aware swizzle: 512 wgs, 8 XCDs, 64 per chunk.
  const int orig = blockIdx.x;
  const int swz = (orig & 7) * 64 + (orig >> 3);
  const int bn = (swz & 15) * 256;   // OUT_F/256 = 16
  const int bm = (swz >> 4) * 256;   // M_ROWS/256 = 32

  // Staging map: wave w, GLL round st covers rows st*64 + w*8 + (lane>>3);
  // LDS chunk lane&7 must hold global chunk (lane&7)^(row&7), row&7==lane>>3.
  const int tr = w * 8 + (lane >> 3);
  const int schnk = (lane & 7) ^ (lane >> 3);
  const signed char* gA = A + (size_t)(bm + tr) * IN_F + schnk * 16;
  const signed char* gB = B + (size_t)(bn + tr) * IN_F + schnk * 16;

  // ds_read bases: A frag f at roA0 + f*4096, B frag g at roB0 + g*4096
  // (asm offset: immediates); per-k-step chunk ch_ks added per cluster.
  const int roA0 = (wm * 128 + r31) * 128;
  const int roB0 = (wn * 64 + r31) * 128;
  const int ch0 = ((0 + khalf) ^ ln7) * 16;
  const int ch1 = ((2 + khalf) ^ ln7) * 16;
  const int ch2 = ((4 + khalf) ^ ln7) * 16;
  const int ch3 = ((6 + khalf) ^ ln7) * 16;

  i32x16 acc[4][2] = {};  // [A-frag f][B-frag g]

#define MFMA1(F, G, AV, BV)                                                  \
  acc[F][G] = __builtin_amdgcn_mfma_i32_32x32x32_i8(AV, BV, acc[F][G], 0, 0, 0)

// 8 MFMAs consuming (a0..a3,b0..b1), interleaved 1:1 with 6 ds_reads into
// (RA0..RA3,RB0,RB1) from base pointers PA/PB.  sched_barrier(0) pins the
// emitted order (rule 18: MFMAs otherwise hoist across asm).
#define CLUSTER_RD(a0, a1, a2, a3, b0, b1, RA0, RA1, RA2, RA3, RB0, RB1,     \
                   PA, PB)                                                   \
  do {                                                                       \
    __builtin_amdgcn_s_setprio(1);                                           \
    MFMA1(0, 0, a0, b0); SB0(); DSRO(RA0, PA, 0);     SB0();                 \
    MFMA1(0, 1, a0, b1); SB0(); DSRO(RA1, PA, 4096);  SB0();                 \
    MFMA1(1, 0, a1, b0); SB0(); DSRO(RA2, PA, 8192);  SB0();                 \
    MFMA1(1, 1, a1, b1); SB0(); DSRO(RA3, PA, 12288); SB0();                 \
    MFMA1(2, 0, a2, b0); SB0(); DSRO(RB0, PB, 0);     SB0();                 \
    MFMA1(2, 1, a2, b1); SB0(); DSRO(RB1, PB, 4096);  SB0();                 \
    MFMA1(3, 0, a3, b0); SB0();                                              \
    MFMA1(3, 1, a3, b1);                                                     \
    __builtin_amdgcn_s_setprio(0);                                           \
  } while (0)

#define CLUSTER(a0, a1, a2, a3, b0, b1)                                      \
  do {                                                                       \
    __builtin_amdgcn_s_setprio(1);                                           \
    MFMA1(0, 0, a0, b0); MFMA1(0, 1, a0, b1);                                \
    MFMA1(1, 0, a1, b0); MFMA1(1, 1, a1, b1);                                \
    MFMA1(2, 0, a2, b0); MFMA1(2, 1, a2, b1);                                \
    MFMA1(3, 0, a3, b0); MFMA1(3, 1, a3, b1);                                \
    __builtin_amdgcn_s_setprio(0);                                           \
  } while (0)

#define RD6P(A0, A1, A2, A3, B0, B1, PA, PB)                                 \
  do {                                                                       \
    DSRO(A0, PA, 0); DSRO(A1, PA, 4096);                                     \
    DSRO(A2, PA, 8192); DSRO(A3, PA, 12288);                                 \
    DSRO(B0, PB, 0); DSRO(B1, PB, 4096);                                     \
  } while (0)

  auto stage4 = [&](const signed char* gsrc, signed char* ldst, int kt) {
#pragma unroll
    for (int st = 0; st < 4; ++st)
      GLL(gsrc + (size_t)(st * 64) * IN_F + (size_t)kt * 128,
          ldst + (st * 64 + w * 8) * 128);
  };

  auto tile = [&](const signed char* SAc, const signed char* SBc,
                  signed char* dA, signed char* dB, int kt, int doStage) {
    const signed char* pA0 = SAc + roA0 + ch0;
    const signed char* pB0 = SBc + roB0 + ch0;
    const signed char* pA1 = SAc + roA0 + ch1;
    const signed char* pB1 = SBc + roB0 + ch1;
    const signed char* pA2 = SAc + roA0 + ch2;
    const signed char* pB2 = SBc + roB0 + ch2;
    const signed char* pA3 = SAc + roA0 + ch3;
    const signed char* pB3 = SBc + roB0 + ch3;
    i32x4 xA0, xA1, xA2, xA3, xB0, xB1;   // set X
    i32x4 yA0, yA1, yA2, yA3, yB0, yB1;   // set Y
    i32x4 zA0, zA1, zA2, zA3, zB0, zB1;   // set Z
    RD6P(xA0, xA1, xA2, xA3, xB0, xB1, pA0, pB0);   // ks0 -> X  (6 out)
    RD6P(yA0, yA1, yA2, yA3, yB0, yB1, pA1, pB1);   // ks1 -> Y  (12 out)
    if (doStage) {
      stage4(gA, dA, kt);
      stage4(gB, dB, kt);
    }
    LGKM(6);                                        // ks0 ready
    CLUSTER_RD(xA0, xA1, xA2, xA3, xB0, xB1,        // MFMA ks0
               zA0, zA1, zA2, zA3, zB0, zB1,        // reads ks2 -> Z
               pA2, pB2);
    LGKM(6);                                        // ks1 ready (out: ks2)
    CLUSTER_RD(yA0, yA1, yA2, yA3, yB0, yB1,        // MFMA ks1
               xA0, xA1, xA2, xA3, xB0, xB1,        // reads ks3 -> X (dead)
               pA3, pB3);
    LGKM(6);                                        // ks2 ready (out: ks3)
    CLUSTER(zA0, zA1, zA2, zA3, zB0, zB1);          // MFMA ks2
    LGKM(0);                                        // ks3 ready
    if (doStage) VM0();                             // buf[nxt] landed
    CLUSTER(xA0, xA1, xA2, xA3, xB0, xB1);          // MFMA ks3
    BARRIER();                                      // after ISSUE only
  };

  // Prologue: buf0 <- tile 0.
  stage4(gA, &sA[0][0], 0);
  stage4(gB, &sB[0][0], 0);
  VM0();
  BARRIER();

#pragma unroll 1
  for (int t2 = 0; t2 < 32; t2 += 2) {
    tile(&sA[0][0], &sB[0][0], &sA[1][0], &sB[1][0], t2 + 1, 1);
    tile(&sA[1][0], &sB[1][0], &sA[0][0], &sB[0][0], t2 + 2, (t2 + 2 < 32));
  }

  // Epilogue: 32x32 D layout col = lane&31, row = (reg&3)+8*(reg>>2)+4*khalf.
#pragma unroll
  for (int f = 0; f < 4; ++f) {
    const int row0 = bm + wm * 128 + f * 32 + 4 * khalf;
#pragma unroll
    for (int g = 0; g < 2; ++g) {
      const int col = bn + wn * 64 + g * 32 + r31;
      const float fc = scale[col] * (1.0f / 127.0f);
      const float bv = bias[col];
#pragma unroll
      for (int reg = 0; reg < 16; ++reg) {
        const int row = row0 + (reg & 3) + 8 * (reg >> 2);
        C[(size_t)row * OUT_F + col] =
            (float)acc[f][g][reg] * (steps[row] * fc) + bv;
      }
    }
  }
#undef MFMA1
#undef CLUSTER_RD
#undef CLUSTER
#undef RD6P
}

extern "C" void kernel_launch(void* const* d_in, const int* in_sizes, int n_in,
                              void* d_out, int out_size, void* d_ws, size_t ws_size,
                              hipStream_t stream) {
  const float* x      = (const float*)d_in[0];   // [4,2048,4096] fp32
  const int* packed   = (const int*)d_in[1];     // [OUT_F*IN_F/2] int32
  const float* scale  = (const float*)d_in[2];   // [OUT_F,1] fp32
  const float* bias   = (const float*)d_in[3];   // [OUT_F] fp32
  float* out = (float*)d_out;                    // [4,2048,4096] fp32

  signed char* Xq = (signed char*)d_ws;                         // 33.5 MB
  signed char* Wq = Xq + (size_t)M_ROWS * IN_F;                 // 16.8 MB
  float* steps = (float*)(Wq + (size_t)OUT_F * IN_F);           // 32 KB

  k_quant_x<<<M_ROWS, 256, 0, stream>>>(x, Xq, steps);
  k_dequant<<<(OUT_F * IN_F / 2) / (256 * 8), 256, 0, stream>>>(packed, Wq);
  k_gemm<<<(OUT_F / 256) * (M_ROWS / 256), 512, 0, stream>>>(
      Xq, Wq, steps, scale, bias, out);
}